// Round 12
// baseline (113.214 us; speedup 1.0000x reference)
//
#include <hip/hip_runtime.h>
#include <math.h>

#define NBATCH 4
#define NV 9
#define DM 64
#define DS 16
// H = W = 32, image = 1024 pixels

typedef float f32x4 __attribute__((ext_vector_type(4)));

__device__ __forceinline__ float softplus_f(float x) {
    return (x > 20.f) ? x : log1pf(__expf(x));
}

__device__ __forceinline__ void gload_lds16(const float* g, float* l) {
    __builtin_amdgcn_global_load_lds(
        (const __attribute__((address_space(1))) void*)g,
        (__attribute__((address_space(3))) void*)l, 16, 0, 0);
}

// ---------------------------------------------------------------------------
// Kernel 0: tabulate A = -exp(log_A_real) and 1/A per (c, n). 1024 entries.
// ---------------------------------------------------------------------------
__global__ void prep_kernel(const float* __restrict__ logA, float2* __restrict__ Atab) {
    int t = threadIdx.x;                       // 1024 threads, 1 block
    float A = -__expf(logA[t]);
    Atab[t] = make_float2(A, __builtin_amdgcn_rcpf(A));
}

// ---------------------------------------------------------------------------
// Kernel 1: fused circular 3x3 convs, ci split 4-ways inside the block.
// Grid: 4(b) * 96(co) * 4(ht) = 1536 blocks, 256 threads.  (~8.5 us measured)
// ---------------------------------------------------------------------------
__global__ __launch_bounds__(256) void conv_kernel(
    const float* __restrict__ u, const float* __restrict__ wd,
    const float* __restrict__ bd, const float* __restrict__ wb,
    const float* __restrict__ wc, const float* __restrict__ dtp,
    float* __restrict__ delta_out, float* __restrict__ Bv_out,
    float* __restrict__ Cv_out)
{
    int bx = blockIdx.x;
    int ht = bx & 3;
    int co = (bx >> 2) % 96;
    int b  = bx / 384;
    int tid = threadIdx.x;
    int chunk = __builtin_amdgcn_readfirstlane(tid >> 6);  // wave-uniform -> SGPR
    int pxt = tid & 63;
    int row = ht * 8 + (pxt >> 3);
    int w0  = (pxt & 7) << 2;

    const float* wbase = (co < 64) ? (wd + (size_t)co * 576)
                       : (co < 80) ? (wb + (size_t)(co - 64) * 576)
                                   : (wc + (size_t)(co - 80) * 576);

    int hm = (row + 31) & 31, hp = (row + 1) & 31;
    int wl = (w0 + 31) & 31;   // col w0-1 (wrapped)
    int wr = (w0 + 4) & 31;    // col w0+4 (wrapped)
    const float* ub = u + (size_t)b * 65536 + (size_t)(chunk << 4) * 1024;
    const float* wq0 = wbase + (size_t)(chunk << 4) * 9;

    float a0 = 0.f, a1 = 0.f, a2 = 0.f, a3 = 0.f;
    #pragma unroll 4
    for (int j = 0; j < 16; ++j) {
        const float* base = ub + j * 1024;
        const float* wq = wq0 + j * 9;
        #pragma unroll
        for (int r = 0; r < 3; ++r) {
            int rr = (r == 0) ? hm : (r == 1) ? row : hp;
            const float* rp = base + rr * 32;
            float4 v = *(const float4*)(rp + w0);
            float L = rp[wl], R = rp[wr];
            float k0 = wq[r * 3 + 0], k1 = wq[r * 3 + 1], k2 = wq[r * 3 + 2];
            a0 = fmaf(k0, L,   fmaf(k1, v.x, fmaf(k2, v.y, a0)));
            a1 = fmaf(k0, v.x, fmaf(k1, v.y, fmaf(k2, v.z, a1)));
            a2 = fmaf(k0, v.y, fmaf(k1, v.z, fmaf(k2, v.w, a2)));
            a3 = fmaf(k0, v.z, fmaf(k1, v.w, fmaf(k2, R,   a3)));
        }
    }

    __shared__ float4 part[4][64];
    part[chunk][pxt] = make_float4(a0, a1, a2, a3);
    __syncthreads();

    if (tid < 64) {
        float4 p0 = part[0][tid], p1 = part[1][tid];
        float4 p2 = part[2][tid], p3 = part[3][tid];
        float s0 = p0.x + p1.x + p2.x + p3.x;
        float s1 = p0.y + p1.y + p2.y + p3.y;
        float s2 = p0.z + p1.z + p2.z + p3.z;
        float s3 = p0.w + p1.w + p2.w + p3.w;
        int prow = ht * 8 + (tid >> 3);
        int pw   = (tid & 7) << 2;
        int pix  = prow * 32 + pw;
        if (co < 64) {
            float bias = bd[co] + dtp[0];
            float4 o;
            o.x = softplus_f(s0 + bias);
            o.y = softplus_f(s1 + bias);
            o.z = softplus_f(s2 + bias);
            o.w = softplus_f(s3 + bias);
            *(float4*)(delta_out + (((size_t)b * 64 + co) << 10) + pix) = o;
        } else if (co < 80) {
            *(float4*)(Bv_out + (((size_t)b * 16 + (co - 64)) << 10) + pix) =
                make_float4(s0, s1, s2, s3);
        } else {
            *(float4*)(Cv_out + (((size_t)b * 16 + (co - 80)) << 10) + pix) =
                make_float4(s0, s1, s2, s3);
        }
    }
}

// ---------------------------------------------------------------------------
// Kernel 2: state update + y reduction — LDS-staged burst version.
// Grid: 36(bi) * 64(c) = 2304 blocks, 256 threads, 64KB LDS each
// (2 blocks/CU resident; stage of next block overlaps compute of current).
// Phase 1: DMA whole (bi,c) channel (16n x 1024px = 64KB) into LDS via
//          global_load_lds dwordx4 -> one contiguous 64KB linear read burst.
// Phase 2: compute from LDS (roll = LDS indexing, no shfl), write s_next as
//          a contiguous 64KB nt-store burst + y float4.
// ---------------------------------------------------------------------------
__global__ __launch_bounds__(256) void scan_kernel(
    const float* __restrict__ u, const float* __restrict__ s_prev,
    const float2* __restrict__ Atab, const float* __restrict__ Dp,
    const float* __restrict__ delta_in, const float* __restrict__ Bv,
    const float* __restrict__ Cv,
    float* __restrict__ y_out, float* __restrict__ s_next)
{
    __shared__ float lds[16][1024];   // 64 KB

    int bx = blockIdx.x;
    int c  = bx & 63;
    int bi = bx >> 6;               // b*9 + i
    int i  = bi % 9;
    int b  = bi / 9;

    int tid = threadIdx.x;
    int wv = tid >> 6;              // wave id (0..3), wave-uniform
    int ln = tid & 63;

    // ---- Phase 1: stage the channel into LDS (contiguous 64KB read burst).
    const float* gsrc = s_prev + ((size_t)(bi * 64 + c) << 14);
    #pragma unroll
    for (int k = 0; k < 16; ++k) {
        gload_lds16(gsrc + (k << 10) + (wv << 8) + (ln << 2),
                    &lds[k][wv << 8]);
    }

    // Overlap with staging latency: support scalars + u/delta loads.
    int pix0 = tid << 2;            // 4 consecutive pixels, one row
    int h  = pix0 >> 5;
    int w0 = pix0 & 31;
    int vx = i / 3 - 1;
    int vy = i % 3 - 1;
    int hh = (h + vy + 32) & 31;

    size_t ub = (((size_t)b * 64 + c) << 10) + pix0;
    f32x4 u4 = *(const f32x4*)(u + ub);
    f32x4 d4 = *(const f32x4*)(delta_in + ub);
    float dk = Dp[c];
    f32x4 y4 = u4 * dk;

    const float2* at  = Atab + (c << 4);              // wave-uniform s_loads
    const float*  bvp = Bv + ((size_t)b << 14) + pix0;
    const float*  cvp = Cv + ((size_t)b << 14) + pix0;
    float*        snb = s_next + ((size_t)(bi * 64 + c) << 14) + pix0;

    __syncthreads();   // waits vmcnt(0) -> LDS fully staged

    int wL = (w0 + 31) & 31;   // col w0-1 (wrapped)
    int wR = (w0 + 4) & 31;    // col w0+4 (wrapped)

    // ---- Phase 2: compute + contiguous nt-store burst.
    #pragma unroll
    for (int n = 0; n < 16; ++n) {
        float2 Ar = at[n];
        f32x4 b4 = *(const f32x4*)(bvp + (n << 10));
        f32x4 c4 = *(const f32x4*)(cvp + (n << 10));

        const float* base = &lds[n][hh << 5];
        f32x4 v = *(const f32x4*)(base + w0);         // 16B-aligned LDS read
        float L = base[wL], R = base[wR];

        float s0, s1, s2, s3;                          // block-uniform branch
        if (vx == 0)      { s0 = v.x; s1 = v.y; s2 = v.z; s3 = v.w; }
        else if (vx > 0)  { s0 = v.y; s1 = v.z; s2 = v.w; s3 = R; }
        else              { s0 = L;   s1 = v.x; s2 = v.y; s3 = v.z; }

        float e0 = __expf(d4.x * Ar.x);
        float e1 = __expf(d4.y * Ar.x);
        float e2 = __expf(d4.z * Ar.x);
        float e3 = __expf(d4.w * Ar.x);

        float bu0 = (e0 - 1.f) * Ar.y * b4.x * u4.x;
        float bu1 = (e1 - 1.f) * Ar.y * b4.y * u4.y;
        float bu2 = (e2 - 1.f) * Ar.y * b4.z * u4.z;
        float bu3 = (e3 - 1.f) * Ar.y * b4.w * u4.w;

        f32x4 sn;
        sn.x = fmaf(e0, s0, bu0);
        sn.y = fmaf(e1, s1, bu1);
        sn.z = fmaf(e2, s2, bu2);
        sn.w = fmaf(e3, s3, bu3);
        __builtin_nontemporal_store(sn, (f32x4*)(snb + (n << 10)));

        y4.x = fmaf(sn.x, c4.x, y4.x);
        y4.y = fmaf(sn.y, c4.y, y4.y);
        y4.z = fmaf(sn.z, c4.z, y4.z);
        y4.w = fmaf(sn.w, c4.w, y4.w);
    }
    __builtin_nontemporal_store(y4,
        (f32x4*)(y_out + (((size_t)(bi * 64 + c)) << 10) + pix0));
}

extern "C" void kernel_launch(void* const* d_in, const int* in_sizes, int n_in,
                              void* d_out, int out_size, void* d_ws, size_t ws_size,
                              hipStream_t stream) {
    const float* u      = (const float*)d_in[0];
    const float* s_prev = (const float*)d_in[1];
    const float* wd     = (const float*)d_in[2];
    const float* bd     = (const float*)d_in[3];
    const float* wb     = (const float*)d_in[4];
    const float* wc     = (const float*)d_in[5];
    const float* logA   = (const float*)d_in[6];
    const float* Dp     = (const float*)d_in[7];
    const float* dtp    = (const float*)d_in[8];

    float* ws    = (float*)d_ws;
    float* delta = ws;                 // 4*64*1024   = 262144 floats
    float* Bv    = ws + 262144;        // 4*16*1024   =  65536 floats
    float* Cv    = ws + 327680;        // 4*16*1024   =  65536 floats
    float2* Atab = (float2*)(ws + 393216);   // 1024 float2 = 8KB

    float* y_out  = (float*)d_out;                            // 4*9*64*1024
    float* s_next = y_out + (size_t)NBATCH * NV * DM * 1024;  // 4*9*64*16*1024

    prep_kernel<<<dim3(1), dim3(1024), 0, stream>>>(logA, Atab);
    conv_kernel<<<dim3(4 * 96 * 4), dim3(256), 0, stream>>>(
        u, wd, bd, wb, wc, dtp, delta, Bv, Cv);
    scan_kernel<<<dim3(36 * 64), dim3(256), 0, stream>>>(
        u, s_prev, Atab, Dp, delta, Bv, Cv, y_out, s_next);
}